// Round 1
// baseline (840.499 us; speedup 1.0000x reference)
//
#include <hip/hip_runtime.h>

// Blocks2Matrix: S=32768 samples, each a 40x40 block scattered (direct +
// transpose) into H[16][2560][2560] f32.
//
// Layout facts (from reference):
//   values[s, mu, p, q]   : s*320 + mu*64 + p*8 + q       (S, 5, 8, 8)
//   cg[a, b, m]           : a*25 + b*5 + m                 (5, 5, 5)
//   block[r, c] = sum_m cg[r%5, c%5, m] * values[s, m, r/5, c/5]
//   H[sys, i*40+r, j*40+c] += block[r,c]
//   H[sys, j*40+c, i*40+r] += block[r,c]   (transpose scatter)

#define SS      32768
#define MU      5
#define NRADC   8
#define NORB    40      // 8*5
#define NSYS    16
#define NATOMS  64
#define NDIM    2560    // 64*40

__global__ __launch_bounds__(320) void b2m_scatter(
    const float* __restrict__ values,
    const float* __restrict__ cg,
    const int*   __restrict__ sys_idx,
    const int*   __restrict__ i_idx,
    const int*   __restrict__ j_idx,
    float*       __restrict__ H)
{
    __shared__ float sv[MU * 64];   // values[s] : [mu][p*8+q]
    __shared__ float scg[125];      // cg        : [a*25 + b*5 + m]

    const int s   = blockIdx.x;
    const int tid = threadIdx.x;

    const float* vsrc = values + (size_t)s * (MU * 64);
    if (tid < MU * 64) sv[tid] = vsrc[tid];
    if (tid < 125)     scg[tid] = cg[tid];
    __syncthreads();

    const int sys = sys_idx[s];
    const int i   = i_idx[s];
    const int j   = j_idx[s];

    float* Hs = H + (size_t)sys * NDIM * NDIM;
    const int rowbase = i * NORB;
    const int colbase = j * NORB;

    // Direct scatter: element e = r*40 + c, lanes walk consecutive c
    // -> contiguous 160B runs per block-row.
    #pragma unroll
    for (int it = 0; it < 5; ++it) {
        const int e = tid + it * 320;
        const int r = e / 40, c = e - r * 40;
        const int p = r / 5,  a = r - p * 5;
        const int q = c / 5,  b = c - q * 5;
        float v = 0.f;
        #pragma unroll
        for (int m = 0; m < 5; ++m)
            v = fmaf(scg[(a * 5 + b) * 5 + m], sv[m * 64 + p * 8 + q], v);
        atomicAdd(Hs + (size_t)(rowbase + r) * NDIM + (colbase + c), v);
    }

    // Transpose scatter: iterate e = c2*40 + r2 (col-major) so the
    // transposed destinations H[colbase+c2][rowbase+r2] are lane-contiguous.
    #pragma unroll
    for (int it = 0; it < 5; ++it) {
        const int e  = tid + it * 320;
        const int c2 = e / 40, r2 = e - c2 * 40;
        const int p = r2 / 5, a = r2 - p * 5;
        const int q = c2 / 5, b = c2 - q * 5;
        float v = 0.f;
        #pragma unroll
        for (int m = 0; m < 5; ++m)
            v = fmaf(scg[(a * 5 + b) * 5 + m], sv[m * 64 + p * 8 + q], v);
        atomicAdd(Hs + (size_t)(colbase + c2) * NDIM + (rowbase + r2), v);
    }
}

extern "C" void kernel_launch(void* const* d_in, const int* in_sizes, int n_in,
                              void* d_out, int out_size, void* d_ws, size_t ws_size,
                              hipStream_t stream) {
    const float* values  = (const float*)d_in[0];
    const float* cg      = (const float*)d_in[1];
    const int*   sys_idx = (const int*)d_in[2];
    const int*   i_idx   = (const int*)d_in[3];
    const int*   j_idx   = (const int*)d_in[4];
    float*       H       = (float*)d_out;

    // d_out is poisoned 0xAA before every launch -> zero it first.
    hipMemsetAsync(H, 0, (size_t)out_size * sizeof(float), stream);

    b2m_scatter<<<SS, 320, 0, stream>>>(values, cg, sys_idx, i_idx, j_idx, H);
}

// Round 3
// 625.213 us; speedup vs baseline: 1.3443x; 1.3443x over previous
//
#include <hip/hip_runtime.h>

// Blocks2Matrix, gather formulation.
//
//   values[s, mu, p, q] : s*320 + mu*64 + p*8 + q   (S, 5, 8, 8) f32
//   cg[a, b, m]         : a*25 + b*5 + m            (5, 5, 5)    f32
//   block[R, C] = sum_m cg[R%5, C%5, m] * values[s, m, R/5, C/5]
//   H[sys, i*40+R, j*40+C] += block[R,C]        (direct)
//   H[sys, j*40+C, i*40+R] += block[R,C]        (transpose)
//
// Gather: destination tile (sys, I, J) output element (r,c) receives
//   direct entries  (s: i=I, j=J):  block[r][c]
//   transpose entries (s: j=I, i=J): block[c][r]
// Each tile owned by one workgroup -> plain stores, no d_out memset.

#define SS      32768
#define MU      5
#define NORB    40
#define NSYS    16
#define NATOMS  64
#define NDIM    2560
#define NBINS   (NSYS * NATOMS * NATOMS)   // 65536
#define CAP     16
#define MAXOVF  8192

// ws layout (bytes):
//   [0,        262144)  counts[NBINS]
//   [262144,   262148)  ovf_count
//   [262272,   327808)  ovf entries int2[MAXOVF]
//   [524288,  4718592)  bins[NBINS*CAP]
#define WS_NEEDED   (524288 + (size_t)NBINS * CAP * 4)

__global__ __launch_bounds__(256) void b2m_fill(
    const int* __restrict__ sys_idx, const int* __restrict__ i_idx,
    const int* __restrict__ j_idx,
    int* __restrict__ counts, int* __restrict__ bins,
    int* __restrict__ ovf_cnt, int2* __restrict__ ovf)
{
    int s = blockIdx.x * blockDim.x + threadIdx.x;
    if (s >= SS) return;
    int sy = sys_idx[s], i = i_idx[s], j = j_idx[s];

    int bd = (sy * NATOMS + i) * NATOMS + j;           // direct tile
    int pos = atomicAdd(&counts[bd], 1);
    if (pos < CAP) bins[bd * CAP + pos] = s;
    else { int o = atomicAdd(ovf_cnt, 1); if (o < MAXOVF) ovf[o] = make_int2(bd, s); }

    int bt = (sy * NATOMS + j) * NATOMS + i;           // transpose tile
    int st = s | 0x10000;
    pos = atomicAdd(&counts[bt], 1);
    if (pos < CAP) bins[bt * CAP + pos] = st;
    else { int o = atomicAdd(ovf_cnt, 1); if (o < MAXOVF) ovf[o] = make_int2(bt, st); }
}

__global__ __launch_bounds__(320) void b2m_gather(
    const float* __restrict__ values, const float* __restrict__ cg,
    const int* __restrict__ counts, const int* __restrict__ bins,
    float* __restrict__ H)
{
    __shared__ float sv[MU * 64];
    __shared__ float scg[125];

    const int bin = blockIdx.x;
    const int tid = threadIdx.x;
    if (tid < 125) scg[tid] = cg[tid];

    const int j  = bin & 63;
    const int i  = (bin >> 6) & 63;
    const int sy = bin >> 12;

    int r_[5], c_[5];
    #pragma unroll
    for (int it = 0; it < 5; ++it) {
        int e = tid + it * 320;
        r_[it] = e / 40;
        c_[it] = e - r_[it] * 40;
    }

    float acc[5] = {0.f, 0.f, 0.f, 0.f, 0.f};
    int n = counts[bin];
    if (n > CAP) n = CAP;
    __syncthreads();   // scg ready

    for (int k = 0; k < n; ++k) {
        int  ent = bins[bin * CAP + k];
        int  s   = ent & 0xFFFF;
        bool tr  = (ent >> 16) != 0;
        sv[tid] = values[(size_t)s * (MU * 64) + tid];
        __syncthreads();
        #pragma unroll
        for (int it = 0; it < 5; ++it) {
            int R = tr ? c_[it] : r_[it];   // block row index
            int C = tr ? r_[it] : c_[it];   // block col index
            int p = R / 5, a = R - p * 5;
            int q = C / 5, b = C - q * 5;
            #pragma unroll
            for (int m = 0; m < 5; ++m)
                acc[it] = fmaf(scg[(a * 5 + b) * 5 + m], sv[m * 64 + p * 8 + q], acc[it]);
        }
        __syncthreads();
    }

    float* Hs = H + (size_t)sy * NDIM * NDIM;
    const int rowbase = i * NORB, colbase = j * NORB;
    #pragma unroll
    for (int it = 0; it < 5; ++it)
        Hs[(size_t)(rowbase + r_[it]) * NDIM + (colbase + c_[it])] = acc[it];
}

__global__ __launch_bounds__(256) void b2m_ovf_apply(
    const float* __restrict__ values, const float* __restrict__ cg,
    const int* __restrict__ ovf_cnt, const int2* __restrict__ ovf,
    float* __restrict__ H)
{
    int n = *ovf_cnt;
    if (n > MAXOVF) n = MAXOVF;
    for (int k = blockIdx.x; k < n; k += gridDim.x) {
        int  bin = ovf[k].x;
        int  ent = ovf[k].y;
        int  s   = ent & 0xFFFF;
        bool tr  = (ent >> 16) != 0;
        int  j = bin & 63, i = (bin >> 6) & 63, sy = bin >> 12;
        const float* vs = values + (size_t)s * (MU * 64);
        float* Hs = H + (size_t)sy * NDIM * NDIM;
        for (int e = threadIdx.x; e < 1600; e += blockDim.x) {
            int rr = e / 40, cc = e - rr * 40;
            int R = tr ? cc : rr, C = tr ? rr : cc;
            int p = R / 5, a = R - p * 5;
            int q = C / 5, b = C - q * 5;
            float v = 0.f;
            for (int m = 0; m < 5; ++m)
                v = fmaf(cg[(a * 5 + b) * 5 + m], vs[m * 64 + p * 8 + q], v);
            atomicAdd(Hs + (size_t)(i * NORB + rr) * NDIM + (j * NORB + cc), v);
        }
    }
}

// ---- round-1 fallback (used only if ws_size is too small) ----
__global__ __launch_bounds__(320) void b2m_scatter(
    const float* __restrict__ values, const float* __restrict__ cg,
    const int* __restrict__ sys_idx, const int* __restrict__ i_idx,
    const int* __restrict__ j_idx, float* __restrict__ H)
{
    __shared__ float sv[MU * 64];
    __shared__ float scg[125];
    const int s = blockIdx.x, tid = threadIdx.x;
    if (tid < MU * 64) sv[tid] = values[(size_t)s * (MU * 64) + tid];
    if (tid < 125) scg[tid] = cg[tid];
    __syncthreads();
    const int sys = sys_idx[s], i = i_idx[s], j = j_idx[s];
    float* Hs = H + (size_t)sys * NDIM * NDIM;
    const int rowbase = i * NORB, colbase = j * NORB;
    #pragma unroll
    for (int it = 0; it < 5; ++it) {
        const int e = tid + it * 320;
        const int r = e / 40, c = e - r * 40;
        const int p = r / 5, a = r - p * 5, q = c / 5, b = c - q * 5;
        float v = 0.f;
        #pragma unroll
        for (int m = 0; m < 5; ++m)
            v = fmaf(scg[(a * 5 + b) * 5 + m], sv[m * 64 + p * 8 + q], v);
        atomicAdd(Hs + (size_t)(rowbase + r) * NDIM + (colbase + c), v);
    }
    #pragma unroll
    for (int it = 0; it < 5; ++it) {
        const int e = tid + it * 320;
        const int c2 = e / 40, r2 = e - c2 * 40;
        const int p = r2 / 5, a = r2 - p * 5, q = c2 / 5, b = c2 - q * 5;
        float v = 0.f;
        #pragma unroll
        for (int m = 0; m < 5; ++m)
            v = fmaf(scg[(a * 5 + b) * 5 + m], sv[m * 64 + p * 8 + q], v);
        atomicAdd(Hs + (size_t)(colbase + c2) * NDIM + (rowbase + r2), v);
    }
}

extern "C" void kernel_launch(void* const* d_in, const int* in_sizes, int n_in,
                              void* d_out, int out_size, void* d_ws, size_t ws_size,
                              hipStream_t stream) {
    const float* values  = (const float*)d_in[0];
    const float* cg      = (const float*)d_in[1];
    const int*   sys_idx = (const int*)d_in[2];
    const int*   i_idx   = (const int*)d_in[3];
    const int*   j_idx   = (const int*)d_in[4];
    float*       H       = (float*)d_out;

    if (ws_size >= WS_NEEDED) {
        char* ws      = (char*)d_ws;
        int*  counts  = (int*)ws;                       // 256 KB
        int*  ovf_cnt = (int*)(ws + 262144);
        int2* ovf     = (int2*)(ws + 262272);
        int*  bins    = (int*)(ws + 524288);

        // zero counts + ovf header (bins are guarded by counts)
        hipMemsetAsync(ws, 0, 262400, stream);

        b2m_fill<<<(SS + 255) / 256, 256, 0, stream>>>(
            sys_idx, i_idx, j_idx, counts, bins, ovf_cnt, ovf);
        b2m_gather<<<NBINS, 320, 0, stream>>>(values, cg, counts, bins, H);
        b2m_ovf_apply<<<64, 256, 0, stream>>>(values, cg, ovf_cnt, ovf, H);
    } else {
        hipMemsetAsync(H, 0, (size_t)out_size * sizeof(float), stream);
        b2m_scatter<<<SS, 320, 0, stream>>>(values, cg, sys_idx, i_idx, j_idx, H);
    }
}